// Round 6
// baseline (309.616 us; speedup 1.0000x reference)
//
#include <hip/hip_runtime.h>

// CausalAttention: x[4,2048,1024] f32, Wq/Wk/Wv [1024,1024] f32 -> out [4,2048,1024] f32
// Round 5: 256^2 tile, BK=64, 8-wave phase-interleaved GEMM (T2 swizzle + T3/T4-style
// per-phase stage/read/MFMA interleave + T5 setprio + T1 XCD swizzle on QKV grid).
// One vmcnt(0)+barrier per K-tile; per-phase raw s_barrier between ds_reads and MFMA.

using f32x4 = __attribute__((ext_vector_type(4))) float;
using s16x8 = __attribute__((ext_vector_type(8))) short;

#define CTX 2048
#define DIM 1024
#define NB 4

__device__ __forceinline__ short f2bf(float f) {
  union { float f; unsigned u; } v; v.f = f;
  unsigned r = (v.u + 0x7fffu + ((v.u >> 16) & 1u)) >> 16;
  return (short)r;
}

__device__ __forceinline__ void async16(const void* g, void* l) {
  __builtin_amdgcn_global_load_lds(
      (const __attribute__((address_space(1))) void*)g,
      (__attribute__((address_space(3))) void*)l, 16, 0, 0);
}

// ---------------- convert kernels ----------------

__global__ __launch_bounds__(256) void cvt_x(const float* __restrict__ in,
                                             short* __restrict__ out, long n8) {
  long i = (long)blockIdx.x * 256 + threadIdx.x;
  if (i >= n8) return;
  const float4* p = (const float4*)in;
  float4 a = p[i * 2], b = p[i * 2 + 1];
  short o[8];
  o[0] = f2bf(a.x); o[1] = f2bf(a.y); o[2] = f2bf(a.z); o[3] = f2bf(a.w);
  o[4] = f2bf(b.x); o[5] = f2bf(b.y); o[6] = f2bf(b.z); o[7] = f2bf(b.w);
  *(int4*)&out[i * 8] = *(int4*)o;
}

// W [1024][1024] f32 -> WT [3072 rows][1024 k] bf16 (stacked Wq^T,Wk^T,Wv^T)
__global__ __launch_bounds__(256) void cvt_wT(const float* __restrict__ Wq,
                                              const float* __restrict__ Wk,
                                              const float* __restrict__ Wv,
                                              short* __restrict__ WT) {
  int z = blockIdx.z;
  const float* W = (z == 0) ? Wq : (z == 1) ? Wk : Wv;
  short* o = WT + (long)z * DIM * DIM;
  __shared__ float t[32][33];
  int n0 = blockIdx.x * 32, k0 = blockIdx.y * 32;
  int tx = threadIdx.x, ty = threadIdx.y;  // block (32,8)
  #pragma unroll
  for (int j = 0; j < 4; ++j)
    t[ty + j * 8][tx] = W[(long)(k0 + ty + j * 8) * DIM + n0 + tx];
  __syncthreads();
  #pragma unroll
  for (int j = 0; j < 4; ++j)
    o[(long)(n0 + ty + j * 8) * DIM + k0 + tx] = f2bf(t[tx][ty + j * 8]);
}

// ---------------- 256^2 GEMM (BT form): C[M,N] = A[M,K] * B[N,K]^T ----------------
// 8 waves (2M x 4N), per-wave C 128x64 = acc[8][4]. LDS [buf][mat][half] of 16KB:
// half = 128 rows x 64 k-cols bf16, st_16x32 XOR-swizzled (byte ^= ((byte>>9)&1)<<5),
// staged linearly via global_load_lds from inverse-swizzled global source.
// Per K-tile: 4 phases (mh,nh) = (0,0),(1,0),(1,1),(0,1); stage A halves of t+1 in
// phase 0, B halves in phase 1. vmcnt(0)+barrier once per K-tile boundary.
// MODE: 2 = fp16 row-major, 3 = f32 row-major, 4 = fused QKV routing epilogue.
#define READ_A(mh)                                                              \
  do {                                                                          \
    _Pragma("unroll") for (int mi = 0; mi < 4; ++mi) {                          \
      _Pragma("unroll") for (int ks = 0; ks < 2; ++ks) {                        \
        aA[mi][ks] = *(const s16x8*)(smem + abase + laneRd +                    \
                                     ((mh)*4 + mi) * 2048 + ks * 64);           \
      }                                                                         \
    }                                                                           \
  } while (0)

#define READ_B(nh)                                                              \
  do {                                                                          \
    _Pragma("unroll") for (int ni = 0; ni < 2; ++ni) {                          \
      _Pragma("unroll") for (int ks = 0; ks < 2; ++ks) {                        \
        bB[ni][ks] = *(const s16x8*)(smem + bbase + laneRd +                    \
                                     ((nh)*2 + ni) * 2048 + ks * 64);           \
      }                                                                         \
    }                                                                           \
  } while (0)

#define DO_MFMA(mh, nh)                                                         \
  do {                                                                          \
    __builtin_amdgcn_s_setprio(1);                                              \
    _Pragma("unroll") for (int mi = 0; mi < 4; ++mi) {                          \
      _Pragma("unroll") for (int ni = 0; ni < 2; ++ni) {                        \
        _Pragma("unroll") for (int ks = 0; ks < 2; ++ks) {                      \
          acc[(mh)*4 + mi][(nh)*2 + ni] = __builtin_amdgcn_mfma_f32_16x16x32_bf16( \
              aA[mi][ks], bB[ni][ks], acc[(mh)*4 + mi][(nh)*2 + ni], 0, 0, 0);  \
        }                                                                       \
      }                                                                         \
    }                                                                           \
    __builtin_amdgcn_s_setprio(0);                                              \
  } while (0)

template <int MODE, bool CSKIP, bool KLIM, bool SWZGRID>
__global__ __launch_bounds__(512, 1) void gemm256(const short* __restrict__ A,
                                                  const short* __restrict__ B,
                                                  void* __restrict__ Cout,
                                                  int K, long sA, long sB, long sC,
                                                  int ldc, int nbx) {
  int bx, by;
  if (SWZGRID) {  // bijective XCD swizzle (grid multiple of 8), column-major decompose
    int wg = ((int)blockIdx.x & 7) * ((int)gridDim.x >> 3) + ((int)blockIdx.x >> 3);
    bx = wg % nbx; by = wg / nbx;
  } else {
    bx = blockIdx.x; by = blockIdx.y;
  }
  const int bz = blockIdx.z;
  if (CSKIP && by > bx) return;  // fully-masked causal block

  const short* Ab = A + bz * sA + (long)bx * 256 * K;
  const short* Bb = B + bz * sB + (long)by * 256 * K;
  const long ldb = (long)K * 2;  // row stride in bytes

  __shared__ __align__(16) char smem[131072];  // [buf][mat][half] * 16384B

  const int tid = threadIdx.x;
  const int lane = tid & 63, wid = tid >> 6;
  const int wm = wid >> 2, wn = wid & 3;         // 2x4 wave grid
  const int frow = lane & 15, kgrp = lane >> 4;  // MFMA fragment indices
  // read-side swizzle: within-half byte b has bit9 = frow bit2 only
  const int xorv = ((frow >> 2) & 1) << 5;
  const int laneRd = frow * 128 + ((kgrp * 16) ^ xorv);
  // stage-side: dest d = s*8192 + tid*16 (linear); source u = d ^ ((d>>9)&1)<<5
  const int sr0 = tid >> 3;
  const int scb = ((tid & 7) << 4) ^ (((tid >> 5) & 1) << 5);

  int kt_end = K >> 6;
  if (KLIM) { int lim = (bx + 1) << 2; if (lim < kt_end) kt_end = lim; }

  f32x4 acc[8][4];
  const f32x4 zero = {0.f, 0.f, 0.f, 0.f};
  #pragma unroll
  for (int mi = 0; mi < 8; ++mi)
    #pragma unroll
    for (int ni = 0; ni < 4; ++ni) acc[mi][ni] = zero;

  // stage one matrix (both halves, 4 loads) of K-tile tt into buffer bn_
  auto STAGE = [&](int bn_, int mat, int tt) {
    const char* mb = (const char*)(mat ? Bb : Ab) + (long)tt * 128 + scb;
    #pragma unroll
    for (int h = 0; h < 2; ++h)
      #pragma unroll
      for (int s = 0; s < 2; ++s)
        async16(mb + (long)(h * 128 + s * 64 + sr0) * ldb,
                smem + ((bn_ * 2 + mat) * 2 + h) * 16384 + s * 8192 + tid * 16);
  };

  // prologue: stage tile 0 into buffer 0
  STAGE(0, 0, 0);
  STAGE(0, 1, 0);
  asm volatile("s_waitcnt vmcnt(0)" ::: "memory");
  __builtin_amdgcn_s_barrier();

  s16x8 aA[4][2], bB[2][2];
  for (int t = 0; t < kt_end; ++t) {
    const int buf = t & 1;
    const int abase = ((buf * 2 + 0) * 2 + wm) * 16384;
    const int bbase = ((buf * 2 + 1) * 2 + (wn >> 1)) * 16384 + (wn & 1) * 8192;
    const int bn = buf ^ 1;
    const bool hn = (t + 1 < kt_end);

    // phase 0: quadrant (0,0); issue A-halves of tile t+1
    if (hn) STAGE(bn, 0, t + 1);
    READ_A(0); READ_B(0);
    __builtin_amdgcn_s_barrier();
    DO_MFMA(0, 0);

    // phase 1: quadrant (1,0) (B regs reused); issue B-halves of tile t+1
    if (hn) STAGE(bn, 1, t + 1);
    READ_A(1);
    __builtin_amdgcn_s_barrier();
    DO_MFMA(1, 0);

    // phase 2: quadrant (1,1) (A regs reused)
    READ_B(1);
    __builtin_amdgcn_s_barrier();
    DO_MFMA(1, 1);

    // phase 3: quadrant (0,1) (B regs reused)
    READ_A(0);
    __builtin_amdgcn_s_barrier();
    DO_MFMA(0, 1);

    // tile boundary: all of tile t+1's staging landed (own loads via vmcnt,
    // all waves' via barrier); WAR safe: reads of buf consumed before barrier.
    asm volatile("s_waitcnt vmcnt(0)" ::: "memory");
    __builtin_amdgcn_s_barrier();
  }

  // epilogue: C/D frag layout col=frow, row=kgrp*4+r (m89-verified)
  const int row0 = bx * 256 + wm * 128;
  const int col0 = by * 256 + wn * 64;
  #pragma unroll
  for (int mi = 0; mi < 8; ++mi) {
    #pragma unroll
    for (int ni = 0; ni < 4; ++ni) {
      #pragma unroll
      for (int r = 0; r < 4; ++r) {
        const int row = row0 + mi * 16 + kgrp * 4 + r;
        const int col = col0 + ni * 16 + frow;
        const float v = acc[mi][ni][r];
        if (MODE == 2) {
          ((_Float16*)Cout)[bz * sC + (long)row * ldc + col] = (_Float16)v;
        } else if (MODE == 3) {
          ((float*)Cout)[bz * sC + (long)row * ldc + col] = v;
        } else {  // MODE 4: fused QKV; row=(b,t); col region: Q | K | V^T
          const long QK = (long)NB * CTX * DIM;
          const int colr = col & 1023;
          long off;
          if (col < 2048) {
            off = (long)(col >> 10) * QK + (long)row * DIM + colr;
          } else {
            off = 2 * QK + (long)(row >> 11) * ((long)DIM * CTX) +
                  (long)colr * CTX + (row & (CTX - 1));
          }
          ((short*)Cout)[off] = f2bf(v);
        }
      }
    }
  }
}

// ---------------- causal softmax, in place: S fp16 -> P bf16 ----------------
// Writes P (incl. exact zeros) out to the 256-block boundary so the 256-row PV
// blocks never read unwritten workspace.
__global__ __launch_bounds__(256) void softmax_causal(void* __restrict__ Sbuf) {
  const int r = blockIdx.x, b = blockIdx.y;
  const long base = (long)b * CTX * CTX + (long)r * CTX;
  _Float16* S = (_Float16*)Sbuf + base;
  short* P = (short*)Sbuf + base;
  const int tid = threadIdx.x;
  const int lane = tid & 63, wid = tid >> 6;
  const int c0 = tid * 8;
  const int ncol = ((r >> 8) + 1) << 8;  // 256-aligned causal boundary
  const float scale = 0.03125f;  // 1/sqrt(1024)

  float v[8];
  if (c0 <= r) {
    _Float16 h[8];
    *(int4*)h = *(const int4*)&S[c0];
    #pragma unroll
    for (int j = 0; j < 8; ++j)
      v[j] = (c0 + j <= r) ? (float)h[j] * scale : -INFINITY;
  } else {
    #pragma unroll
    for (int j = 0; j < 8; ++j) v[j] = -INFINITY;
  }
  float m = -INFINITY;
  #pragma unroll
  for (int j = 0; j < 8; ++j) m = fmaxf(m, v[j]);
  #pragma unroll
  for (int off = 32; off >= 1; off >>= 1) m = fmaxf(m, __shfl_xor(m, off));
  __shared__ float redm[4], reds[4];
  if (lane == 0) redm[wid] = m;
  __syncthreads();
  m = fmaxf(fmaxf(redm[0], redm[1]), fmaxf(redm[2], redm[3]));

  float p[8];
  float s = 0.f;
  #pragma unroll
  for (int j = 0; j < 8; ++j) {
    p[j] = exp2f((v[j] - m) * 1.44269504f);
    s += p[j];
  }
  #pragma unroll
  for (int off = 32; off >= 1; off >>= 1) s += __shfl_xor(s, off);
  if (lane == 0) reds[wid] = s;
  __syncthreads();
  s = reds[0] + reds[1] + reds[2] + reds[3];
  const float inv = 1.0f / s;

  if (c0 < ncol) {
    short o[8];
    #pragma unroll
    for (int j = 0; j < 8; ++j) o[j] = f2bf(p[j] * inv);
    *(int4*)&P[c0] = *(int4*)o;
  }
}

// ---------------- launch ----------------
extern "C" void kernel_launch(void* const* d_in, const int* in_sizes, int n_in,
                              void* d_out, int out_size, void* d_ws, size_t ws_size,
                              hipStream_t stream) {
  (void)in_sizes; (void)n_in; (void)out_size; (void)ws_size;
  const float* x  = (const float*)d_in[0];
  const float* Wq = (const float*)d_in[1];
  const float* Wk = (const float*)d_in[2];
  const float* Wv = (const float*)d_in[3];

  const long MB = 1024 * 1024;
  char* ws = (char*)d_ws;
  short* xb = (short*)(ws + 0);         // 16 MB  [8192][1024] bf16
  short* WT = (short*)(ws + 16 * MB);   //  6 MB  [3072][1024] bf16 (Wq^T,Wk^T,Wv^T)
  short* Qb = (short*)(ws + 24 * MB);   // 16 MB  [4][2048][1024] bf16
  short* Kb = (short*)(ws + 40 * MB);   // 16 MB  (contiguous after Qb)
  short* Vt = (short*)(ws + 56 * MB);   // 16 MB  [4][1024 e][2048 t] bf16 (V^T)
  void*  S  = (void*)(ws + 72 * MB);    // 32 MB  [4][2048][2048] fp16 -> bf16 P

  // 1) x -> bf16
  cvt_x<<<4096, 256, 0, stream>>>(x, xb, (long)NB * CTX * DIM / 8);
  // 2) W -> W^T bf16 (stacked)
  cvt_wT<<<dim3(32, 32, 3), dim3(32, 8), 0, stream>>>(Wq, Wk, Wv, WT);
  // 3) fused QKV: [8192,1024] @ [3072,1024]^T, 32x12=384 blocks, XCD-swizzled
  gemm256<4, false, false, true><<<384, 512, 0, stream>>>(
      xb, WT, Qb, DIM, 0, 0, 0, DIM, 32);
  // 4) S = Q K^T -> fp16, lower-triangular 256-blocks only
  gemm256<2, true, false, false><<<dim3(8, 8, NB), 512, 0, stream>>>(
      Qb, Kb, S, DIM, (long)CTX * DIM, (long)CTX * DIM, (long)CTX * CTX, CTX, 0);
  // 5) causal softmax in place (fp16 scores -> bf16 P, zero-filled to 256 boundary)
  softmax_causal<<<dim3(CTX, NB), 256, 0, stream>>>(S);
  // 6) O = P V via V^T (M=2048, N=1024, K=2048), K-tiles causally limited
  gemm256<3, false, true, false><<<dim3(8, 4, NB), 512, 0, stream>>>(
      (short*)S, Vt, d_out, CTX, (long)CTX * CTX, (long)DIM * CTX, (long)CTX * DIM, DIM, 0);
}